// Round 3
// baseline (1900.940 us; speedup 1.0000x reference)
//
#include <hip/hip_runtime.h>
#include <math.h>
#include <stdint.h>

#define NN 50000
#define NE 800000
#define HEADS 4

typedef __attribute__((ext_vector_type(8))) short bf16x8;
typedef __attribute__((ext_vector_type(4))) float f32x4;

__device__ __forceinline__ uint32_t bf16rne(float x) {
  uint32_t b = __float_as_uint(x);
  return (b + 0x7FFFu + ((b >> 16) & 1u)) >> 16;
}
__device__ __forceinline__ float bflo(uint32_t v) {  // low ushort -> float
  return __uint_as_float(v << 16);
}
__device__ __forceinline__ float bfhi(uint32_t v) {  // high ushort -> float
  return __uint_as_float(v & 0xFFFF0000u);
}

// ---------------- CSR build (by dst) ----------------
__global__ void hist_kernel(const int* __restrict__ dst, int* __restrict__ counts, int n) {
  int i = blockIdx.x * blockDim.x + threadIdx.x;
  if (i < n) atomicAdd(&counts[dst[i]], 1);
}

// single-block exclusive scan, shuffle-based
__global__ void scan_kernel(const int* __restrict__ counts, int* __restrict__ row_ptr, int n) {
  __shared__ int wsum[16];
  const int lane = threadIdx.x & 63;
  const int w = threadIdx.x >> 6;
  int carry = 0;
  for (int start = 0; start < n; start += 1024) {
    int i = start + (int)threadIdx.x;
    int v = (i < n) ? counts[i] : 0;
    int x = v;
#pragma unroll
    for (int off = 1; off < 64; off <<= 1) {
      int t = __shfl_up(x, off);
      if (lane >= off) x += t;
    }
    if (lane == 63) wsum[w] = x;
    __syncthreads();
    if (w == 0 && lane < 16) {
      int s = wsum[lane];
#pragma unroll
      for (int off = 1; off < 16; off <<= 1) {
        int t = __shfl_up(s, off);
        if (lane >= off) s += t;
      }
      wsum[lane] = s;
    }
    __syncthreads();
    int woff = (w > 0) ? wsum[w - 1] : 0;
    int incl = x + woff;
    if (i < n) row_ptr[i] = carry + incl - v;
    carry += wsum[15];
    __syncthreads();
  }
  if (threadIdx.x == 0) row_ptr[n] = carry;
}

__global__ void scatter_kernel(const int* __restrict__ dst, const int* __restrict__ src,
                               const int* __restrict__ row_ptr, int* __restrict__ cursor,
                               int* __restrict__ srcs, int n) {
  int i = blockIdx.x * blockDim.x + threadIdx.x;
  if (i < n) {
    int d = dst[i];
    int pos = atomicAdd(&cursor[d], 1);
    srcs[row_ptr[d] + pos] = src[i];
  }
}

// ---------------- B pre-split: B[K][N] fp32 -> BT3[512][K3p] bf16 triples ----------------
__global__ void build_bt3(const float* __restrict__ B, unsigned short* __restrict__ BT3,
                          int K, int N, int K3p) {
  int kp = blockIdx.x * blockDim.x + threadIdx.x;
  int n = blockIdx.y;
  if (kp >= K3p) return;
  unsigned short out = 0;
  if (n < N && kp < 3 * K) {
    int k = kp / 3;
    int r = kp - 3 * k;
    float v = B[(size_t)k * N + n];
    uint32_t hi = bf16rne(v);
    if (r == 1) {
      float back = __uint_as_float(hi << 16);
      out = (unsigned short)bf16rne(v - back);
    } else {
      out = (unsigned short)hi;
    }
  }
  BT3[(size_t)n * K3p + kp] = out;
}

// ---------------- split-bf16x3 MFMA GEMM, bf16 output (head-padded layout) ----------------
// Ch[M][RSc] (bf16) = A[M][K] @ B; logical col c (< NstR) stored at h*DHP + (c - h*DHR),
// h = (c*magic)>>12.
__global__ __launch_bounds__(256, 2) void gemm_split3(
    const float* __restrict__ A, const unsigned short* __restrict__ BT3,
    unsigned short* __restrict__ Ch, int M, int K, int K3p, int NstR, int RSc,
    int DHR, int DHP, int magic) {
  __shared__ unsigned short As[128 * 96];  // [m][k'] rows of 192 B
  __shared__ unsigned short Bs[128 * 96];  // [n][k'] rows of 192 B
  const int tid = threadIdx.x;
  const int w = tid >> 6, lane = tid & 63;
  const int wr = w >> 1, wc = w & 1;
  const int ln = lane & 15, quad = lane >> 4;
  const int m0 = blockIdx.y * 128, n0 = blockIdx.x * 128;
  const int ar = tid >> 1, ah = tid & 1;
  const long arow = (long)min(m0 + ar, M - 1) * K;

  f32x4 acc[4][4];
#pragma unroll
  for (int mi = 0; mi < 4; ++mi)
#pragma unroll
    for (int ni = 0; ni < 4; ++ni) acc[mi][ni] = (f32x4){0.f, 0.f, 0.f, 0.f};

  const int ksteps = (K + 31) / 32;
  for (int s = 0; s < ksteps; ++s) {
    const int k0 = s * 32;
    const int kp0 = s * 96;
#pragma unroll
    for (int j = 0; j < 6; ++j) {
      int g = (w * 6 + j) * 64 + lane;
      unsigned row = ((unsigned)g * 5462u) >> 16;  // g / 12
      unsigned col = (unsigned)g - row * 12u;
      const unsigned short* gp = BT3 + (size_t)(n0 + row) * K3p + kp0 + col * 8;
      void* lp = (void*)((char*)Bs + (size_t)(w * 6 + j) * 1024);
      __builtin_amdgcn_global_load_lds(
          (const __attribute__((address_space(1))) void*)gp,
          (__attribute__((address_space(3))) void*)lp, 16, 0, 0);
    }
    {
      float f[16];
      const int kb = k0 + ah * 16;
#pragma unroll
      for (int q = 0; q < 4; ++q) {
        int gk = kb + q * 4;
        if (gk + 3 < K) {
          *(float4*)&f[q * 4] = *(const float4*)&A[arow + gk];
        } else {
#pragma unroll
          for (int t = 0; t < 4; ++t) f[q * 4 + t] = (gk + t < K) ? A[arow + gk + t] : 0.f;
        }
      }
      unsigned short tr[48];
#pragma unroll
      for (int j = 0; j < 16; ++j) {
        uint32_t hi = bf16rne(f[j]);
        float back = __uint_as_float(hi << 16);
        uint32_t lo = bf16rne(f[j] - back);
        tr[3 * j + 0] = (unsigned short)hi;
        tr[3 * j + 1] = (unsigned short)hi;
        tr[3 * j + 2] = (unsigned short)lo;
      }
      uint32_t u[24];
#pragma unroll
      for (int i = 0; i < 24; ++i)
        u[i] = (uint32_t)tr[2 * i] | ((uint32_t)tr[2 * i + 1] << 16);
      uint4* dst = (uint4*)((char*)As + ar * 192 + ah * 96);
#pragma unroll
      for (int t = 0; t < 6; ++t) dst[t] = *(uint4*)&u[t * 4];
    }
    __syncthreads();
#pragma unroll
    for (int sub = 0; sub < 3; ++sub) {
      bf16x8 af[4], bfr[4];
#pragma unroll
      for (int mi = 0; mi < 4; ++mi)
        af[mi] = *(const bf16x8*)&As[(wr * 64 + mi * 16 + ln) * 96 + sub * 32 + quad * 8];
#pragma unroll
      for (int ni = 0; ni < 4; ++ni)
        bfr[ni] = *(const bf16x8*)&Bs[(wc * 64 + ni * 16 + ln) * 96 + sub * 32 + quad * 8];
#pragma unroll
      for (int mi = 0; mi < 4; ++mi)
#pragma unroll
        for (int ni = 0; ni < 4; ++ni)
          acc[mi][ni] =
              __builtin_amdgcn_mfma_f32_16x16x32_bf16(af[mi], bfr[ni], acc[mi][ni], 0, 0, 0);
    }
    __syncthreads();
  }
  // epilogue: single fp32->bf16 rounding from MFMA accumulator; head-padded column mapping
#pragma unroll
  for (int mi = 0; mi < 4; ++mi) {
#pragma unroll
    for (int r = 0; r < 4; ++r) {
      int gm = m0 + wr * 64 + mi * 16 + quad * 4 + r;
      if (gm < M) {
        unsigned short* crow = Ch + (size_t)gm * RSc;
#pragma unroll
        for (int ni = 0; ni < 4; ++ni) {
          int gn = n0 + wc * 64 + ni * 16 + ln;
          if (gn < NstR) {
            int h = (gn * magic) >> 12;
            int col = h * DHP + (gn - h * DHR);
            crow[col] = (unsigned short)bf16rne(acc[mi][ni][r]);
          }
        }
      }
    }
  }
}

// ---------------- el/er from bf16 proj (head-padded rows) ----------------
template <int DHR, int DHP>
__global__ void el_er_kernel(const unsigned short* __restrict__ projh,
                             const float* __restrict__ al, const float* __restrict__ ar,
                             float* __restrict__ el, float* __restrict__ er) {
  int t = blockIdx.x * blockDim.x + threadIdx.x;  // t = n*HEADS + h
  if (t >= NN * HEADS) return;
  int h = t & (HEADS - 1);
  int n = t >> 2;
  const unsigned short* pr = projh + (size_t)n * (HEADS * DHP) + (size_t)h * DHP;
  const float* alh = al + h * DHR;
  const float* arh = ar + h * DHR;
  float sl = 0.f, sr = 0.f;
#pragma unroll 4
  for (int d = 0; d < DHR; d += 4) {
    uint2 pv = *(const uint2*)&pr[d];
    float p0 = bflo(pv.x), p1 = bfhi(pv.x), p2 = bflo(pv.y), p3 = bfhi(pv.y);
    float4 av = *(const float4*)&alh[d];
    float4 rv = *(const float4*)&arh[d];
    sl += p0 * av.x + p1 * av.y + p2 * av.z + p3 * av.w;
    sr += p0 * rv.x + p1 * rv.y + p2 * rv.z + p3 * rv.w;
  }
  el[t] = sl;
  er[t] = sr;
}

// ---------------- fused edge softmax + aggregation, persistent waves ----------------
// One wave per node (work-stolen via atomic counter). 64 lanes x uint4 = full 4-head
// row per gather. Per 16-edge chunk: p-phase (lane = (edge,head) worker) computes
// exp/leaky; next chunk's srcs+el are prefetched while current chunk's 16 row-gathers
// are in flight (removes 2 of 3 serial latencies from the chunk critical path).
template <int DHP, int DHR, bool ACT>
__global__ __launch_bounds__(256) void aggregate3(
    const unsigned short* __restrict__ projh, const float* __restrict__ el,
    const float* __restrict__ er, const float* __restrict__ bias,
    const int* __restrict__ row_ptr, const int* __restrict__ srcs,
    float* __restrict__ out, int* __restrict__ ctr) {
  constexpr int LPH = DHP / 8;          // uint4 lanes per head (13 or 16)
  constexpr int RS = HEADS * DHP * 2;   // row stride bytes (832 or 1024)
  const int lane = threadIdx.x & 63;
  // p-phase role: edge e16 = lane>>2, head hp = lane&3
  const int e16 = lane >> 2, hp = lane & 3;
  // gather-phase role: head, uint4-index u within head
  int head;
  if constexpr (LPH == 16) head = lane >> 4;
  else head = (lane * 5) >> 6;  // lane/13, exact for lane<64
  const int u = lane - head * LPH;
  const int laneByte = head * (DHP * 2) + u * 16;
  const bool active = lane < 4 * LPH;
  const char* pb = (const char*)projh;

  // bias (loaded once per wave; predicated to avoid OOB on padded tail)
  float bv[8];
  const int d0 = u * 8;
#pragma unroll
  for (int j = 0; j < 8; ++j)
    bv[j] = (active && d0 + j < DHR) ? bias[head * DHR + d0 + j] : 0.f;

  for (;;) {
    int n_;
    if (lane == 0) n_ = atomicAdd(ctr, 1);
    const int node = __shfl(n_, 0);
    if (node >= NN) break;

    const int beg = row_ptr[node], end = row_ptr[node + 1];
    const float er_p = er[node * 4 + hp];

    float acc[8];
#pragma unroll
    for (int j = 0; j < 8; ++j) acc[j] = 0.f;
    float lsum = 0.f;

    int i = beg;
    int rem = end - beg;
    // prefetch chunk 0 p-inputs
    int sE = 0;
    float elv = 0.f;
    if (rem > 0 && e16 < rem) {
      sE = srcs[i + e16];
      elv = el[sE * 4 + hp];
    }
    while (rem > 0) {
      const int take = rem < 16 ? rem : 16;
      // ---- p-phase from prefetched inputs ----
      float ev = elv + er_p;
      ev = fmaxf(ev, 0.2f * ev);
      const float pv_ = (e16 < take) ? __expf(ev) : 0.f;
      const int off_ = sE * RS;
      // ---- prefetch next chunk's srcs + el ----
      const int i2 = i + take;
      const int rem2 = rem - take;
      int sEn = 0;
      float elvn = 0.f;
      if (rem2 > 0 && e16 < rem2) {
        sEn = srcs[i2 + e16];
        elvn = el[sEn * 4 + hp];
      }
      // ---- gather phase ----
      if (take == 16) {
#pragma unroll
        for (int e = 0; e < 16; ++e) {
          const int sl = e * 4 + head;
          const float pv = __shfl(pv_, sl);
          const int off = __shfl(off_, sl);
          uint4 q = *(const uint4*)(pb + (uint32_t)(off + laneByte));
          lsum += pv;
          acc[0] += pv * bflo(q.x);
          acc[1] += pv * bfhi(q.x);
          acc[2] += pv * bflo(q.y);
          acc[3] += pv * bfhi(q.y);
          acc[4] += pv * bflo(q.z);
          acc[5] += pv * bfhi(q.z);
          acc[6] += pv * bflo(q.w);
          acc[7] += pv * bfhi(q.w);
        }
      } else {
        for (int e = 0; e < take; ++e) {
          const int sl = e * 4 + head;
          const float pv = __shfl(pv_, sl);
          const int off = __shfl(off_, sl);
          uint4 q = *(const uint4*)(pb + (uint32_t)(off + laneByte));
          lsum += pv;
          acc[0] += pv * bflo(q.x);
          acc[1] += pv * bfhi(q.x);
          acc[2] += pv * bflo(q.y);
          acc[3] += pv * bfhi(q.y);
          acc[4] += pv * bflo(q.z);
          acc[5] += pv * bfhi(q.z);
          acc[6] += pv * bflo(q.w);
          acc[7] += pv * bfhi(q.w);
        }
      }
      sE = sEn;
      elv = elvn;
      i = i2;
      rem = rem2;
    }

    const float inv = 1.f / (lsum + 1e-9f);
    if (active) {
      float o[8];
#pragma unroll
      for (int j = 0; j < 8; ++j) {
        float v = acc[j] * inv + bv[j];
        if (ACT) v = (v > 0.f) ? v : 0.2f * v;
        o[j] = v;
      }
      float* orow = out + (size_t)node * (HEADS * DHR) + head * DHR + d0;
      *(float4*)orow = make_float4(o[0], o[1], o[2], o[3]);
      if (d0 + 7 < DHR) *(float4*)(orow + 4) = make_float4(o[4], o[5], o[6], o[7]);
    }
  }
}

extern "C" void kernel_launch(void* const* d_in, const int* in_sizes, int n_in,
                              void* d_out, int out_size, void* d_ws, size_t ws_size,
                              hipStream_t stream) {
  const float* init_emb = (const float*)d_in[0];
  const float* W1 = (const float*)d_in[1];
  const float* al1 = (const float*)d_in[2];
  const float* ar1 = (const float*)d_in[3];
  const float* b1 = (const float*)d_in[4];
  const float* W2 = (const float*)d_in[5];
  const float* al2 = (const float*)d_in[6];
  const float* ar2 = (const float*)d_in[7];
  const float* b2 = (const float*)d_in[8];
  const int* src = (const int*)d_in[9];
  const int* dst = (const int*)d_in[10];
  float* out = (float*)d_out;

  // workspace carve-up (~138 MB)
  char* ws = (char*)d_ws;
  size_t off = 0;
  auto alloc = [&](size_t bytes) {
    void* p = ws + off;
    off += (bytes + 255) & ~((size_t)255);
    return p;
  };
  unsigned short* projh = (unsigned short*)alloc((size_t)NN * 512 * 2);  // bf16 proj (both layers)
  float* x1 = (float*)alloc((size_t)NN * 400 * 4);
  float* el = (float*)alloc((size_t)NN * HEADS * 4);
  float* er = (float*)alloc((size_t)NN * HEADS * 4);
  unsigned short* BT3 = (unsigned short*)alloc((size_t)512 * 1248 * 2);
  int* row_ptr = (int*)alloc((size_t)(NN + 1) * 4);
  int* counts = (int*)alloc((size_t)NN * 4);
  int* srcs = (int*)alloc((size_t)NE * 4);
  int* ctr = (int*)alloc(256);

  // --- CSR build ---
  hipMemsetAsync(counts, 0, (size_t)NN * 4, stream);
  hist_kernel<<<(NE + 255) / 256, 256, 0, stream>>>(dst, counts, NE);
  scan_kernel<<<1, 1024, 0, stream>>>(counts, row_ptr, NN);
  hipMemsetAsync(counts, 0, (size_t)NN * 4, stream);
  scatter_kernel<<<(NE + 255) / 256, 256, 0, stream>>>(dst, src, row_ptr, counts, srcs, NE);

  // --- layer 1: K=300 -> K3p=960, N=400 (head-padded 4x104) ---
  build_bt3<<<dim3((960 + 255) / 256, 512), 256, 0, stream>>>(W1, BT3, 300, 400, 960);
  gemm_split3<<<dim3(4, (NN + 127) / 128), 256, 0, stream>>>(init_emb, BT3, projh, NN, 300, 960,
                                                             400, 416, 100, 104, 41);
  el_er_kernel<100, 104><<<(NN * HEADS + 255) / 256, 256, 0, stream>>>(projh, al1, ar1, el, er);
  hipMemsetAsync(ctr, 0, 4, stream);
  aggregate3<104, 100, true><<<2048, 256, 0, stream>>>(projh, el, er, b1, row_ptr, srcs, x1, ctr);

  // --- layer 2: K=400 -> K3p=1248, N=512 (no padding needed) ---
  build_bt3<<<dim3((1248 + 255) / 256, 512), 256, 0, stream>>>(W2, BT3, 400, 512, 1248);
  gemm_split3<<<dim3(4, (NN + 127) / 128), 256, 0, stream>>>(x1, BT3, projh, NN, 400, 1248,
                                                             512, 512, 128, 128, 32);
  el_er_kernel<128, 128><<<(NN * HEADS + 255) / 256, 256, 0, stream>>>(projh, al2, ar2, el, er);
  hipMemsetAsync(ctr, 0, 4, stream);
  aggregate3<128, 128, false><<<2048, 256, 0, stream>>>(projh, el, er, b2, row_ptr, srcs, out, ctr);
}

// Round 4
// 797.366 us; speedup vs baseline: 2.3840x; 2.3840x over previous
//
#include <hip/hip_runtime.h>
#include <math.h>
#include <stdint.h>

#define NN 50000
#define NE 800000
#define HEADS 4
#define MPAD 50048  // NN rounded up to 128

typedef __attribute__((ext_vector_type(8))) short bf16x8;
typedef __attribute__((ext_vector_type(4))) float f32x4;

__device__ __forceinline__ uint32_t bf16rne(float x) {
  uint32_t b = __float_as_uint(x);
  return (b + 0x7FFFu + ((b >> 16) & 1u)) >> 16;
}
__device__ __forceinline__ float bflo(uint32_t v) {  // low ushort -> float
  return __uint_as_float(v << 16);
}
__device__ __forceinline__ float bfhi(uint32_t v) {  // high ushort -> float
  return __uint_as_float(v & 0xFFFF0000u);
}

// ---------------- CSR build (by dst) ----------------
__global__ void hist_kernel(const int* __restrict__ dst, int* __restrict__ counts, int n) {
  int i = blockIdx.x * blockDim.x + threadIdx.x;
  if (i < n) atomicAdd(&counts[dst[i]], 1);
}

// single-block exclusive scan, shuffle-based
__global__ void scan_kernel(const int* __restrict__ counts, int* __restrict__ row_ptr, int n) {
  __shared__ int wsum[16];
  const int lane = threadIdx.x & 63;
  const int w = threadIdx.x >> 6;
  int carry = 0;
  for (int start = 0; start < n; start += 1024) {
    int i = start + (int)threadIdx.x;
    int v = (i < n) ? counts[i] : 0;
    int x = v;
#pragma unroll
    for (int off = 1; off < 64; off <<= 1) {
      int t = __shfl_up(x, off);
      if (lane >= off) x += t;
    }
    if (lane == 63) wsum[w] = x;
    __syncthreads();
    if (w == 0 && lane < 16) {
      int s = wsum[lane];
#pragma unroll
      for (int off = 1; off < 16; off <<= 1) {
        int t = __shfl_up(s, off);
        if (lane >= off) s += t;
      }
      wsum[lane] = s;
    }
    __syncthreads();
    int woff = (w > 0) ? wsum[w - 1] : 0;
    int incl = x + woff;
    if (i < n) row_ptr[i] = carry + incl - v;
    carry += wsum[15];
    __syncthreads();
  }
  if (threadIdx.x == 0) row_ptr[n] = carry;
}

__global__ void scatter_kernel(const int* __restrict__ dst, const int* __restrict__ src,
                               const int* __restrict__ row_ptr, int* __restrict__ cursor,
                               int* __restrict__ srcs, int n) {
  int i = blockIdx.x * blockDim.x + threadIdx.x;
  if (i < n) {
    int d = dst[i];
    int pos = atomicAdd(&cursor[d], 1);
    srcs[row_ptr[d] + pos] = src[i];
  }
}

// ---------------- pair-split presplit: X[M][K] fp32 -> X2[m][s-block 128B] ----------------
// Per 32-k block s: 8 granules of 16B; granule (c*4+q) ^ (m&7) holds {hi,lo}[k=s*32+q*8..+7].
// XOR swizzle is baked into the GLOBAL layout so global_load_lds staging is linear (m173).
__global__ void presplit_pairs(const float* __restrict__ X, unsigned short* __restrict__ X2,
                               int M, int K, int ksteps) {
  const int m = blockIdx.y;
  const int t = threadIdx.x;  // t = s*4 + q
  if (t >= ksteps * 4) return;
  const int s = t >> 2, q = t & 3;
  const int kb = s * 32 + q * 8;
  float v[8];
#pragma unroll
  for (int j = 0; j < 8; ++j) {
    int k = kb + j;
    v[j] = (m < M && k < K) ? X[(size_t)m * K + k] : 0.f;
  }
  uint32_t hi[8], lo[8];
#pragma unroll
  for (int j = 0; j < 8; ++j) {
    hi[j] = bf16rne(v[j]);
    float back = __uint_as_float(hi[j] << 16);
    lo[j] = bf16rne(v[j] - back);
  }
  uint4 hp, lp;
  hp.x = hi[0] | (hi[1] << 16);
  hp.y = hi[2] | (hi[3] << 16);
  hp.z = hi[4] | (hi[5] << 16);
  hp.w = hi[6] | (hi[7] << 16);
  lp.x = lo[0] | (lo[1] << 16);
  lp.y = lo[2] | (lo[3] << 16);
  lp.z = lo[4] | (lo[5] << 16);
  lp.w = lo[6] | (lo[7] << 16);
  char* rowp = (char*)X2 + (size_t)m * (ksteps * 128) + s * 128;
  const int x = m & 7;
  *(uint4*)(rowp + ((q ^ x) << 4)) = hp;
  *(uint4*)(rowp + (((4 | q) ^ x) << 4)) = lp;
}

// B variant: W[K][N] fp32, row n of output = column n of W. Rows n >= N are zero.
__global__ void presplit_pairs_b(const float* __restrict__ W, unsigned short* __restrict__ B2,
                                 int K, int N, int ksteps) {
  const int n = blockIdx.y;
  const int t = threadIdx.x;
  if (t >= ksteps * 4) return;
  const int s = t >> 2, q = t & 3;
  const int kb = s * 32 + q * 8;
  float v[8];
#pragma unroll
  for (int j = 0; j < 8; ++j) {
    int k = kb + j;
    v[j] = (n < N && k < K) ? W[(size_t)k * N + n] : 0.f;
  }
  uint32_t hi[8], lo[8];
#pragma unroll
  for (int j = 0; j < 8; ++j) {
    hi[j] = bf16rne(v[j]);
    float back = __uint_as_float(hi[j] << 16);
    lo[j] = bf16rne(v[j] - back);
  }
  uint4 hp, lp;
  hp.x = hi[0] | (hi[1] << 16);
  hp.y = hi[2] | (hi[3] << 16);
  hp.z = hi[4] | (hi[5] << 16);
  hp.w = hi[6] | (hi[7] << 16);
  lp.x = lo[0] | (lo[1] << 16);
  lp.y = lo[2] | (lo[3] << 16);
  lp.z = lo[4] | (lo[5] << 16);
  lp.w = lo[6] | (lo[7] << 16);
  char* rowp = (char*)B2 + (size_t)n * (ksteps * 128) + s * 128;
  const int x = n & 7;
  *(uint4*)(rowp + ((q ^ x) << 4)) = hp;
  *(uint4*)(rowp + (((4 | q) ^ x) << 4)) = lp;
}

// ---------------- pair-split MFMA GEMM, bf16 output (head-padded layout) ----------------
// C = A@B via hi*hi + hi*lo + lo*hi. Both operands staged by 16B global_load_lds
// from pre-swizzled pair layout; ds_reads XOR-deswizzle (2-way conflicts = free).
__global__ __launch_bounds__(256, 2) void gemm_pairs(
    const unsigned short* __restrict__ A2, const unsigned short* __restrict__ B2,
    unsigned short* __restrict__ Ch, int M, int ksteps, int NstR, int RSc,
    int DHR, int DHP, int magic) {
  __shared__ unsigned short As[8192];  // 128 rows x 128B (hi|lo granules, swizzled)
  __shared__ unsigned short Bs[8192];
  const int tid = threadIdx.x;
  const int w = tid >> 6, lane = tid & 63;
  const int wr = w >> 1, wc = w & 1;
  const int ln = lane & 15, quad = lane >> 4;
  const int m0 = blockIdx.y * 128, n0 = blockIdx.x * 128;
  const long strideB = (long)ksteps * 128;  // bytes per row
  // staging: t16 = w*4+j in [0,16); granules g = t16*64+lane; row = g>>3, gran = g&7
  // per load: 8 consecutive rows, lane's global addr = row*strideB + s*128 + gran*16

  f32x4 acc[4][4];
#pragma unroll
  for (int mi = 0; mi < 4; ++mi)
#pragma unroll
    for (int ni = 0; ni < 4; ++ni) acc[mi][ni] = (f32x4){0.f, 0.f, 0.f, 0.f};

  const int xa = ln & 7;
  const int gA0 = (quad ^ xa) << 4, gA1 = ((4 | quad) ^ xa) << 4;

  for (int s = 0; s < ksteps; ++s) {
    const long sb = (long)s * 128;
#pragma unroll
    for (int j = 0; j < 4; ++j) {
      const int t16 = w * 4 + j;
      const int row = t16 * 8 + (lane >> 3);
      const int gran = lane & 7;
      const char* gpA = (const char*)A2 + (size_t)(m0 + row) * strideB + sb + gran * 16;
      const char* gpB = (const char*)B2 + (size_t)(n0 + row) * strideB + sb + gran * 16;
      __builtin_amdgcn_global_load_lds(
          (const __attribute__((address_space(1))) void*)gpA,
          (__attribute__((address_space(3))) void*)((char*)As + t16 * 1024), 16, 0, 0);
      __builtin_amdgcn_global_load_lds(
          (const __attribute__((address_space(1))) void*)gpB,
          (__attribute__((address_space(3))) void*)((char*)Bs + t16 * 1024), 16, 0, 0);
    }
    __syncthreads();
    bf16x8 ah[4], alo[4], bh[4], blo[4];
#pragma unroll
    for (int mi = 0; mi < 4; ++mi) {
      const int rA = wr * 64 + mi * 16 + ln;
      ah[mi] = *(const bf16x8*)((const char*)As + rA * 128 + gA0);
      alo[mi] = *(const bf16x8*)((const char*)As + rA * 128 + gA1);
    }
#pragma unroll
    for (int ni = 0; ni < 4; ++ni) {
      const int rB = wc * 64 + ni * 16 + ln;
      bh[ni] = *(const bf16x8*)((const char*)Bs + rB * 128 + gA0);
      blo[ni] = *(const bf16x8*)((const char*)Bs + rB * 128 + gA1);
    }
#pragma unroll
    for (int mi = 0; mi < 4; ++mi)
#pragma unroll
      for (int ni = 0; ni < 4; ++ni)
        acc[mi][ni] = __builtin_amdgcn_mfma_f32_16x16x32_bf16(ah[mi], bh[ni], acc[mi][ni], 0, 0, 0);
#pragma unroll
    for (int mi = 0; mi < 4; ++mi)
#pragma unroll
      for (int ni = 0; ni < 4; ++ni)
        acc[mi][ni] = __builtin_amdgcn_mfma_f32_16x16x32_bf16(ah[mi], blo[ni], acc[mi][ni], 0, 0, 0);
#pragma unroll
    for (int mi = 0; mi < 4; ++mi)
#pragma unroll
      for (int ni = 0; ni < 4; ++ni)
        acc[mi][ni] = __builtin_amdgcn_mfma_f32_16x16x32_bf16(alo[mi], bh[ni], acc[mi][ni], 0, 0, 0);
    __syncthreads();
  }
  // epilogue: fp32->bf16 rounding; head-padded column mapping
#pragma unroll
  for (int mi = 0; mi < 4; ++mi) {
#pragma unroll
    for (int r = 0; r < 4; ++r) {
      int gm = m0 + wr * 64 + mi * 16 + quad * 4 + r;
      if (gm < M) {
        unsigned short* crow = Ch + (size_t)gm * RSc;
#pragma unroll
        for (int ni = 0; ni < 4; ++ni) {
          int gn = n0 + wc * 64 + ni * 16 + ln;
          if (gn < NstR) {
            int h = (gn * magic) >> 12;
            int col = h * DHP + (gn - h * DHR);
            crow[col] = (unsigned short)bf16rne(acc[mi][ni][r]);
          }
        }
      }
    }
  }
}

// ---------------- el/er from bf16 proj (head-padded rows) ----------------
template <int DHR, int DHP>
__global__ void el_er_kernel(const unsigned short* __restrict__ projh,
                             const float* __restrict__ al, const float* __restrict__ ar,
                             float* __restrict__ el, float* __restrict__ er) {
  int t = blockIdx.x * blockDim.x + threadIdx.x;  // t = n*HEADS + h
  if (t >= NN * HEADS) return;
  int h = t & (HEADS - 1);
  int n = t >> 2;
  const unsigned short* pr = projh + (size_t)n * (HEADS * DHP) + (size_t)h * DHP;
  const float* alh = al + h * DHR;
  const float* arh = ar + h * DHR;
  float sl = 0.f, sr = 0.f;
#pragma unroll 4
  for (int d = 0; d < DHR; d += 4) {
    uint2 pv = *(const uint2*)&pr[d];
    float p0 = bflo(pv.x), p1 = bfhi(pv.x), p2 = bflo(pv.y), p3 = bfhi(pv.y);
    float4 av = *(const float4*)&alh[d];
    float4 rv = *(const float4*)&arh[d];
    sl += p0 * av.x + p1 * av.y + p2 * av.z + p3 * av.w;
    sr += p0 * rv.x + p1 * rv.y + p2 * rv.z + p3 * rv.w;
  }
  el[t] = sl;
  er[t] = sr;
}

// ---------------- fused edge softmax + aggregation, one wave per node ----------------
// blockIdx-mapped (no atomics). 64 lanes x uint4 = full 4-head row per gather.
// Per 16-edge chunk: p-phase computes exp/leaky; next chunk's srcs+el prefetched
// while current chunk's row-gathers are in flight.
template <int DHP, int DHR, bool ACT>
__global__ __launch_bounds__(256) void aggregate2(
    const unsigned short* __restrict__ projh, const float* __restrict__ el,
    const float* __restrict__ er, const float* __restrict__ bias,
    const int* __restrict__ row_ptr, const int* __restrict__ srcs,
    float* __restrict__ out) {
  constexpr int LPH = DHP / 8;          // uint4 lanes per head (13 or 16)
  constexpr int RS = HEADS * DHP * 2;   // row stride bytes (832 or 1024)
  const int node = blockIdx.x * 4 + (threadIdx.x >> 6);
  if (node >= NN) return;
  const int lane = threadIdx.x & 63;
  const int beg = row_ptr[node], end = row_ptr[node + 1];
  // p-phase role: edge e16 = lane>>2, head hp = lane&3
  const int e16 = lane >> 2, hp = lane & 3;
  const float er_p = er[node * 4 + hp];
  // gather-phase role: head, uint4-index u within head
  int head;
  if constexpr (LPH == 16) head = lane >> 4;
  else head = (lane * 5) >> 6;  // lane/13, exact for lane<64
  const int u = lane - head * LPH;
  const int laneByte = head * (DHP * 2) + u * 16;
  const bool active = lane < 4 * LPH;
  const char* pb = (const char*)projh;

  // bias (predicated: avoid OOB on padded tail)
  float bv[8];
  const int d0 = u * 8;
#pragma unroll
  for (int j = 0; j < 8; ++j)
    bv[j] = (active && d0 + j < DHR) ? bias[head * DHR + d0 + j] : 0.f;

  float acc[8];
#pragma unroll
  for (int j = 0; j < 8; ++j) acc[j] = 0.f;
  float lsum = 0.f;

  int i = beg;
  int rem = end - beg;
  // prefetch chunk 0 p-inputs
  int sE = 0;
  float elv = 0.f;
  if (rem > 0 && e16 < rem) {
    sE = srcs[i + e16];
    elv = el[sE * 4 + hp];
  }
  while (rem > 0) {
    const int take = rem < 16 ? rem : 16;
    // ---- p-phase from prefetched inputs ----
    float ev = elv + er_p;
    ev = fmaxf(ev, 0.2f * ev);
    const float pv_ = (e16 < take) ? __expf(ev) : 0.f;
    const int off_ = sE * RS;
    // ---- prefetch next chunk's srcs + el ----
    const int i2 = i + take;
    const int rem2 = rem - take;
    int sEn = 0;
    float elvn = 0.f;
    if (rem2 > 0 && e16 < rem2) {
      sEn = srcs[i2 + e16];
      elvn = el[sEn * 4 + hp];
    }
    // ---- gather phase ----
    if (take == 16) {
#pragma unroll
      for (int e = 0; e < 16; ++e) {
        const int sl = e * 4 + head;
        const float pv = __shfl(pv_, sl);
        const int off = __shfl(off_, sl);
        uint4 q = *(const uint4*)(pb + (uint32_t)(off + laneByte));
        lsum += pv;
        acc[0] += pv * bflo(q.x);
        acc[1] += pv * bfhi(q.x);
        acc[2] += pv * bflo(q.y);
        acc[3] += pv * bfhi(q.y);
        acc[4] += pv * bflo(q.z);
        acc[5] += pv * bfhi(q.z);
        acc[6] += pv * bflo(q.w);
        acc[7] += pv * bfhi(q.w);
      }
    } else {
      for (int e = 0; e < take; ++e) {
        const int sl = e * 4 + head;
        const float pv = __shfl(pv_, sl);
        const int off = __shfl(off_, sl);
        uint4 q = *(const uint4*)(pb + (uint32_t)(off + laneByte));
        lsum += pv;
        acc[0] += pv * bflo(q.x);
        acc[1] += pv * bfhi(q.x);
        acc[2] += pv * bflo(q.y);
        acc[3] += pv * bfhi(q.y);
        acc[4] += pv * bflo(q.z);
        acc[5] += pv * bfhi(q.z);
        acc[6] += pv * bflo(q.w);
        acc[7] += pv * bfhi(q.w);
      }
    }
    sE = sEn;
    elv = elvn;
    i = i2;
    rem = rem2;
  }

  const float inv = 1.f / (lsum + 1e-9f);
  if (active) {
    float o[8];
#pragma unroll
    for (int j = 0; j < 8; ++j) {
      float v = acc[j] * inv + bv[j];
      if (ACT) v = (v > 0.f) ? v : 0.2f * v;
      o[j] = v;
    }
    float* orow = out + (size_t)node * (HEADS * DHR) + head * DHR + d0;
    *(float4*)orow = make_float4(o[0], o[1], o[2], o[3]);
    if (d0 + 7 < DHR) *(float4*)(orow + 4) = make_float4(o[4], o[5], o[6], o[7]);
  }
}

extern "C" void kernel_launch(void* const* d_in, const int* in_sizes, int n_in,
                              void* d_out, int out_size, void* d_ws, size_t ws_size,
                              hipStream_t stream) {
  const float* init_emb = (const float*)d_in[0];
  const float* W1 = (const float*)d_in[1];
  const float* al1 = (const float*)d_in[2];
  const float* ar1 = (const float*)d_in[3];
  const float* b1 = (const float*)d_in[4];
  const float* W2 = (const float*)d_in[5];
  const float* al2 = (const float*)d_in[6];
  const float* ar2 = (const float*)d_in[7];
  const float* b2 = (const float*)d_in[8];
  const int* src = (const int*)d_in[9];
  const int* dst = (const int*)d_in[10];
  float* out = (float*)d_out;

  // workspace carve-up (~138 MB); A2 pair-split buffers live in d_out (dead until
  // the final aggregate, which only reads projh/el/er and then overwrites it).
  char* ws = (char*)d_ws;
  size_t off = 0;
  auto alloc = [&](size_t bytes) {
    void* p = ws + off;
    off += (bytes + 255) & ~((size_t)255);
    return p;
  };
  unsigned short* projh = (unsigned short*)alloc((size_t)NN * 512 * 2);  // bf16 proj (both layers)
  float* x1 = (float*)alloc((size_t)NN * 400 * 4);
  float* el = (float*)alloc((size_t)NN * HEADS * 4);
  float* er = (float*)alloc((size_t)NN * HEADS * 4);
  unsigned short* B2 = (unsigned short*)alloc((size_t)512 * 13 * 128);  // max ksteps=13
  int* row_ptr = (int*)alloc((size_t)(NN + 1) * 4);
  int* counts = (int*)alloc((size_t)NN * 4);
  int* srcs = (int*)alloc((size_t)NE * 4);
  unsigned short* A2 = (unsigned short*)d_out;  // up to MPAD*13*128 = 83.3MB <= 102.4MB

  // --- CSR build ---
  hipMemsetAsync(counts, 0, (size_t)NN * 4, stream);
  hist_kernel<<<(NE + 255) / 256, 256, 0, stream>>>(dst, counts, NE);
  scan_kernel<<<1, 1024, 0, stream>>>(counts, row_ptr, NN);
  hipMemsetAsync(counts, 0, (size_t)NN * 4, stream);
  scatter_kernel<<<(NE + 255) / 256, 256, 0, stream>>>(dst, src, row_ptr, counts, srcs, NE);

  // --- layer 1: K=300 -> ksteps=10, N=400 (head-padded 4x104) ---
  presplit_pairs<<<dim3(1, MPAD), 64, 0, stream>>>(init_emb, A2, NN, 300, 10);
  presplit_pairs_b<<<dim3(1, 512), 64, 0, stream>>>(W1, B2, 300, 400, 10);
  gemm_pairs<<<dim3(4, MPAD / 128), 256, 0, stream>>>(A2, B2, projh, NN, 10, 400, 416, 100, 104, 41);
  el_er_kernel<100, 104><<<(NN * HEADS + 255) / 256, 256, 0, stream>>>(projh, al1, ar1, el, er);
  aggregate2<104, 100, true><<<(NN + 3) / 4, 256, 0, stream>>>(projh, el, er, b1, row_ptr, srcs, x1);

  // --- layer 2: K=400 -> ksteps=13, N=512 ---
  presplit_pairs<<<dim3(1, MPAD), 64, 0, stream>>>(x1, A2, NN, 400, 13);
  presplit_pairs_b<<<dim3(1, 512), 64, 0, stream>>>(W2, B2, 400, 512, 13);
  gemm_pairs<<<dim3(4, MPAD / 128), 256, 0, stream>>>(A2, B2, projh, NN, 13, 512, 512, 128, 128, 32);
  el_er_kernel<128, 128><<<(NN * HEADS + 255) / 256, 256, 0, stream>>>(projh, al2, ar2, el, er);
  aggregate2<128, 128, false><<<(NN + 3) / 4, 256, 0, stream>>>(projh, el, er, b2, row_ptr, srcs, out);
}

// Round 5
// 774.442 us; speedup vs baseline: 2.4546x; 1.0296x over previous
//
#include <hip/hip_runtime.h>
#include <math.h>
#include <stdint.h>

#define NN 50000
#define NE 800000
#define HEADS 4
#define MPAD 50048  // NN rounded up to 128

typedef __attribute__((ext_vector_type(8))) short bf16x8;
typedef __attribute__((ext_vector_type(4))) float f32x4;

__device__ __forceinline__ uint32_t bf16rne(float x) {
  uint32_t b = __float_as_uint(x);
  return (b + 0x7FFFu + ((b >> 16) & 1u)) >> 16;
}
__device__ __forceinline__ float bflo(uint32_t v) {  // low ushort -> float
  return __uint_as_float(v << 16);
}
__device__ __forceinline__ float bfhi(uint32_t v) {  // high ushort -> float
  return __uint_as_float(v & 0xFFFF0000u);
}

// ---------------- CSR build (by dst) ----------------
__global__ void hist_kernel(const int* __restrict__ dst, int* __restrict__ counts, int n) {
  int i = blockIdx.x * blockDim.x + threadIdx.x;
  if (i < n) atomicAdd(&counts[dst[i]], 1);
}

// single-block exclusive scan, shuffle-based
__global__ void scan_kernel(const int* __restrict__ counts, int* __restrict__ row_ptr, int n) {
  __shared__ int wsum[16];
  const int lane = threadIdx.x & 63;
  const int w = threadIdx.x >> 6;
  int carry = 0;
  for (int start = 0; start < n; start += 1024) {
    int i = start + (int)threadIdx.x;
    int v = (i < n) ? counts[i] : 0;
    int x = v;
#pragma unroll
    for (int off = 1; off < 64; off <<= 1) {
      int t = __shfl_up(x, off);
      if (lane >= off) x += t;
    }
    if (lane == 63) wsum[w] = x;
    __syncthreads();
    if (w == 0 && lane < 16) {
      int s = wsum[lane];
#pragma unroll
      for (int off = 1; off < 16; off <<= 1) {
        int t = __shfl_up(s, off);
        if (lane >= off) s += t;
      }
      wsum[lane] = s;
    }
    __syncthreads();
    int woff = (w > 0) ? wsum[w - 1] : 0;
    int incl = x + woff;
    if (i < n) row_ptr[i] = carry + incl - v;
    carry += wsum[15];
    __syncthreads();
  }
  if (threadIdx.x == 0) row_ptr[n] = carry;
}

__global__ void scatter_kernel(const int* __restrict__ dst, const int* __restrict__ src,
                               const int* __restrict__ row_ptr, int* __restrict__ cursor,
                               int* __restrict__ srcs, int n) {
  int i = blockIdx.x * blockDim.x + threadIdx.x;
  if (i < n) {
    int d = dst[i];
    int pos = atomicAdd(&cursor[d], 1);
    srcs[row_ptr[d] + pos] = src[i];
  }
}

// ---------------- pair-split presplit: X[M][K] fp32 -> X2[m][s-block 128B] ----------------
// Per 32-k block s: 8 granules of 16B; granule q^(m&7) holds hi, (4|q)^(m&7) holds lo.
// XOR swizzle baked into the GLOBAL layout so global_load_lds staging is linear (m173).
// Fat grid-stride version: one wave per row per iteration.
__global__ void presplit_pairs(const float* __restrict__ X, unsigned short* __restrict__ X2,
                               int M, int Mpad, int K, int ksteps) {
  const int wid = blockIdx.x * (blockDim.x >> 6) + (threadIdx.x >> 6);
  const int nw = gridDim.x * (blockDim.x >> 6);
  const int t = threadIdx.x & 63;
  const int s = t >> 2, q = t & 3;
  const bool act = t < ksteps * 4;
  const int kb = s * 32 + q * 8;
  for (int m = wid; m < Mpad; m += nw) {
    if (!act) continue;
    float v[8];
#pragma unroll
    for (int j = 0; j < 8; ++j) {
      int k = kb + j;
      v[j] = (m < M && k < K) ? X[(size_t)m * K + k] : 0.f;
    }
    uint32_t hi[8], lo[8];
#pragma unroll
    for (int j = 0; j < 8; ++j) {
      hi[j] = bf16rne(v[j]);
      float back = __uint_as_float(hi[j] << 16);
      lo[j] = bf16rne(v[j] - back);
    }
    uint4 hp, lp;
    hp.x = hi[0] | (hi[1] << 16);
    hp.y = hi[2] | (hi[3] << 16);
    hp.z = hi[4] | (hi[5] << 16);
    hp.w = hi[6] | (hi[7] << 16);
    lp.x = lo[0] | (lo[1] << 16);
    lp.y = lo[2] | (lo[3] << 16);
    lp.z = lo[4] | (lo[5] << 16);
    lp.w = lo[6] | (lo[7] << 16);
    char* rowp = (char*)X2 + (size_t)m * (ksteps * 128) + s * 128;
    const int x = m & 7;
    *(uint4*)(rowp + ((q ^ x) << 4)) = hp;
    *(uint4*)(rowp + (((4 | q) ^ x) << 4)) = lp;
  }
}

// B variant (layer 1): W[K][N] fp32, row n = column n of W; rows n >= N zero.
__global__ void presplit_pairs_b(const float* __restrict__ W, unsigned short* __restrict__ B2,
                                 int K, int N, int ksteps) {
  const int n = blockIdx.y;
  const int t = threadIdx.x;
  if (t >= ksteps * 4) return;
  const int s = t >> 2, q = t & 3;
  const int kb = s * 32 + q * 8;
  float v[8];
#pragma unroll
  for (int j = 0; j < 8; ++j) {
    int k = kb + j;
    v[j] = (n < N && k < K) ? W[(size_t)k * N + n] : 0.f;
  }
  uint32_t hi[8], lo[8];
#pragma unroll
  for (int j = 0; j < 8; ++j) {
    hi[j] = bf16rne(v[j]);
    float back = __uint_as_float(hi[j] << 16);
    lo[j] = bf16rne(v[j] - back);
  }
  uint4 hp, lp;
  hp.x = hi[0] | (hi[1] << 16);
  hp.y = hi[2] | (hi[3] << 16);
  hp.z = hi[4] | (hi[5] << 16);
  hp.w = hi[6] | (hi[7] << 16);
  lp.x = lo[0] | (lo[1] << 16);
  lp.y = lo[2] | (lo[3] << 16);
  lp.z = lo[4] | (lo[5] << 16);
  lp.w = lo[6] | (lo[7] << 16);
  char* rowp = (char*)B2 + (size_t)n * (ksteps * 128) + s * 128;
  const int x = n & 7;
  *(uint4*)(rowp + ((q ^ x) << 4)) = hp;
  *(uint4*)(rowp + (((4 | q) ^ x) << 4)) = lp;
}

// B variant (layer 2): head-padded K' = h*104 + d (d<100 real, else zero), K'=416, ksteps=13.
__global__ void presplit_pairs_b2(const float* __restrict__ W, unsigned short* __restrict__ B2) {
  const int n = blockIdx.y;  // 512 rows
  const int t = threadIdx.x;
  if (t >= 52) return;
  const int s = t >> 2, q = t & 3;
  const int kb = s * 32 + q * 8;
  float v[8];
#pragma unroll
  for (int j = 0; j < 8; ++j) {
    int kp = kb + j;
    int h = kp / 104;
    int d = kp - h * 104;
    v[j] = (d < 100) ? W[(size_t)(h * 100 + d) * 512 + n] : 0.f;
  }
  uint32_t hi[8], lo[8];
#pragma unroll
  for (int j = 0; j < 8; ++j) {
    hi[j] = bf16rne(v[j]);
    float back = __uint_as_float(hi[j] << 16);
    lo[j] = bf16rne(v[j] - back);
  }
  uint4 hp, lp;
  hp.x = hi[0] | (hi[1] << 16);
  hp.y = hi[2] | (hi[3] << 16);
  hp.z = hi[4] | (hi[5] << 16);
  hp.w = hi[6] | (hi[7] << 16);
  lp.x = lo[0] | (lo[1] << 16);
  lp.y = lo[2] | (lo[3] << 16);
  lp.z = lo[4] | (lo[5] << 16);
  lp.w = lo[6] | (lo[7] << 16);
  char* rowp = (char*)B2 + (size_t)n * 1664 + s * 128;
  const int x = n & 7;
  *(uint4*)(rowp + ((q ^ x) << 4)) = hp;
  *(uint4*)(rowp + (((4 | q) ^ x) << 4)) = lp;
}

// ---------------- pair-split MFMA GEMM, bf16 output (head-padded layout) ----------------
// C = A@B via hi*hi + hi*lo + lo*hi. Both operands staged by 16B global_load_lds
// from pre-swizzled pair layout; ds_reads XOR-deswizzle (2-way conflicts = free).
__global__ __launch_bounds__(256, 2) void gemm_pairs(
    const unsigned short* __restrict__ A2, const unsigned short* __restrict__ B2,
    unsigned short* __restrict__ Ch, int M, int ksteps, int NstR, int RSc,
    int DHR, int DHP, int magic) {
  __shared__ unsigned short As[8192];  // 128 rows x 128B (hi|lo granules, swizzled)
  __shared__ unsigned short Bs[8192];
  const int tid = threadIdx.x;
  const int w = tid >> 6, lane = tid & 63;
  const int wr = w >> 1, wc = w & 1;
  const int ln = lane & 15, quad = lane >> 4;
  const int m0 = blockIdx.y * 128, n0 = blockIdx.x * 128;
  const long strideB = (long)ksteps * 128;  // bytes per row

  f32x4 acc[4][4];
#pragma unroll
  for (int mi = 0; mi < 4; ++mi)
#pragma unroll
    for (int ni = 0; ni < 4; ++ni) acc[mi][ni] = (f32x4){0.f, 0.f, 0.f, 0.f};

  const int xa = ln & 7;
  const int gA0 = (quad ^ xa) << 4, gA1 = ((4 | quad) ^ xa) << 4;

  for (int s = 0; s < ksteps; ++s) {
    const long sb = (long)s * 128;
#pragma unroll
    for (int j = 0; j < 4; ++j) {
      const int t16 = w * 4 + j;
      const int row = t16 * 8 + (lane >> 3);
      const int gran = lane & 7;
      const char* gpA = (const char*)A2 + (size_t)(m0 + row) * strideB + sb + gran * 16;
      const char* gpB = (const char*)B2 + (size_t)(n0 + row) * strideB + sb + gran * 16;
      __builtin_amdgcn_global_load_lds(
          (const __attribute__((address_space(1))) void*)gpA,
          (__attribute__((address_space(3))) void*)((char*)As + t16 * 1024), 16, 0, 0);
      __builtin_amdgcn_global_load_lds(
          (const __attribute__((address_space(1))) void*)gpB,
          (__attribute__((address_space(3))) void*)((char*)Bs + t16 * 1024), 16, 0, 0);
    }
    __syncthreads();
    bf16x8 ah[4], alo[4], bh[4], blo[4];
#pragma unroll
    for (int mi = 0; mi < 4; ++mi) {
      const int rA = wr * 64 + mi * 16 + ln;
      ah[mi] = *(const bf16x8*)((const char*)As + rA * 128 + gA0);
      alo[mi] = *(const bf16x8*)((const char*)As + rA * 128 + gA1);
    }
#pragma unroll
    for (int ni = 0; ni < 4; ++ni) {
      const int rB = wc * 64 + ni * 16 + ln;
      bh[ni] = *(const bf16x8*)((const char*)Bs + rB * 128 + gA0);
      blo[ni] = *(const bf16x8*)((const char*)Bs + rB * 128 + gA1);
    }
#pragma unroll
    for (int mi = 0; mi < 4; ++mi)
#pragma unroll
      for (int ni = 0; ni < 4; ++ni)
        acc[mi][ni] = __builtin_amdgcn_mfma_f32_16x16x32_bf16(ah[mi], bh[ni], acc[mi][ni], 0, 0, 0);
#pragma unroll
    for (int mi = 0; mi < 4; ++mi)
#pragma unroll
      for (int ni = 0; ni < 4; ++ni)
        acc[mi][ni] = __builtin_amdgcn_mfma_f32_16x16x32_bf16(ah[mi], blo[ni], acc[mi][ni], 0, 0, 0);
#pragma unroll
    for (int mi = 0; mi < 4; ++mi)
#pragma unroll
      for (int ni = 0; ni < 4; ++ni)
        acc[mi][ni] = __builtin_amdgcn_mfma_f32_16x16x32_bf16(alo[mi], bh[ni], acc[mi][ni], 0, 0, 0);
    __syncthreads();
  }
  // epilogue: fp32->bf16 rounding; head-padded column mapping
#pragma unroll
  for (int mi = 0; mi < 4; ++mi) {
#pragma unroll
    for (int r = 0; r < 4; ++r) {
      int gm = m0 + wr * 64 + mi * 16 + quad * 4 + r;
      if (gm < M) {
        unsigned short* crow = Ch + (size_t)gm * RSc;
#pragma unroll
        for (int ni = 0; ni < 4; ++ni) {
          int gn = n0 + wc * 64 + ni * 16 + ln;
          if (gn < NstR) {
            int h = (gn * magic) >> 12;
            int col = h * DHP + (gn - h * DHR);
            crow[col] = (unsigned short)bf16rne(acc[mi][ni][r]);
          }
        }
      }
    }
  }
}

// ---------------- el/er from bf16 proj (head-padded rows) ----------------
template <int DHR, int DHP>
__global__ void el_er_kernel(const unsigned short* __restrict__ projh,
                             const float* __restrict__ al, const float* __restrict__ ar,
                             float* __restrict__ el, float* __restrict__ er) {
  int t = blockIdx.x * blockDim.x + threadIdx.x;  // t = n*HEADS + h
  if (t >= NN * HEADS) return;
  int h = t & (HEADS - 1);
  int n = t >> 2;
  const unsigned short* pr = projh + (size_t)n * (HEADS * DHP) + (size_t)h * DHP;
  const float* alh = al + h * DHR;
  const float* arh = ar + h * DHR;
  float sl = 0.f, sr = 0.f;
#pragma unroll 4
  for (int d = 0; d < DHR; d += 4) {
    uint2 pv = *(const uint2*)&pr[d];
    float p0 = bflo(pv.x), p1 = bfhi(pv.x), p2 = bflo(pv.y), p3 = bfhi(pv.y);
    float4 av = *(const float4*)&alh[d];
    float4 rv = *(const float4*)&arh[d];
    sl += p0 * av.x + p1 * av.y + p2 * av.z + p3 * av.w;
    sr += p0 * rv.x + p1 * rv.y + p2 * rv.z + p3 * rv.w;
  }
  el[t] = sl;
  er[t] = sr;
}

// ---------------- fused edge softmax + aggregation, one wave per node ----------------
// blockIdx-mapped. 64 lanes x uint4 = full 4-head row per gather. Per 16-edge chunk:
// p-phase computes exp/leaky; next chunk's srcs+el prefetched while gathers in flight.
// EMIT: instead of fp32 output rows, emit the layer-2 pair-split A2 layout directly
// (head-padded K' = h*104 + u*8; XOR-swizzled granules, stride 1664B) — this fuses
// the layer-2 presplit and eliminates the x1 fp32 round-trip.
template <int DHP, int DHR, bool ACT, bool EMIT>
__global__ __launch_bounds__(256) void aggregate2(
    const unsigned short* __restrict__ projh, const float* __restrict__ el,
    const float* __restrict__ er, const float* __restrict__ bias,
    const int* __restrict__ row_ptr, const int* __restrict__ srcs,
    float* __restrict__ out, unsigned short* __restrict__ a2) {
  constexpr int LPH = DHP / 8;          // uint4 lanes per head (13 or 16)
  constexpr int RS = HEADS * DHP * 2;   // row stride bytes (832 or 1024)
  const int node = blockIdx.x * 4 + (threadIdx.x >> 6);
  if (node >= NN) return;
  const int lane = threadIdx.x & 63;
  const int beg = row_ptr[node], end = row_ptr[node + 1];
  // p-phase role: edge e16 = lane>>2, head hp = lane&3
  const int e16 = lane >> 2, hp = lane & 3;
  const float er_p = er[node * 4 + hp];
  // gather-phase role: head, uint4-index u within head
  int head;
  if constexpr (LPH == 16) head = lane >> 4;
  else head = (lane * 5) >> 6;  // lane/13, exact for lane<64
  const int u = lane - head * LPH;
  const bool active = lane < 4 * LPH;
  // inactive lanes gather byte 0 of the row (same lines as lanes 0-3: no extra traffic)
  const int laneByte = active ? head * (DHP * 2) + u * 16 : 0;
  const char* pb = (const char*)projh;

  // bias (predicated: avoid OOB on padded tail)
  float bv[8];
  const int d0 = u * 8;
#pragma unroll
  for (int j = 0; j < 8; ++j)
    bv[j] = (active && d0 + j < DHR) ? bias[head * DHR + d0 + j] : 0.f;

  float acc[8];
#pragma unroll
  for (int j = 0; j < 8; ++j) acc[j] = 0.f;
  float lsum = 0.f;

  int i = beg;
  int rem = end - beg;
  // prefetch chunk 0 p-inputs
  int sE = 0;
  float elv = 0.f;
  if (rem > 0 && e16 < rem) {
    sE = srcs[i + e16];
    elv = el[sE * 4 + hp];
  }
  while (rem > 0) {
    const int take = rem < 16 ? rem : 16;
    // ---- p-phase from prefetched inputs ----
    float ev = elv + er_p;
    ev = fmaxf(ev, 0.2f * ev);
    const float pv_ = (e16 < take) ? __expf(ev) : 0.f;
    const int off_ = sE * RS;
    // ---- prefetch next chunk's srcs + el ----
    const int i2 = i + take;
    const int rem2 = rem - take;
    int sEn = 0;
    float elvn = 0.f;
    if (rem2 > 0 && e16 < rem2) {
      sEn = srcs[i2 + e16];
      elvn = el[sEn * 4 + hp];
    }
    // ---- gather phase ----
    if (take == 16) {
#pragma unroll
      for (int e = 0; e < 16; ++e) {
        const int sl = e * 4 + head;
        const float pv = __shfl(pv_, sl);
        const int off = __shfl(off_, sl);
        uint4 q = *(const uint4*)(pb + (uint32_t)(off + laneByte));
        lsum += pv;
        acc[0] += pv * bflo(q.x);
        acc[1] += pv * bfhi(q.x);
        acc[2] += pv * bflo(q.y);
        acc[3] += pv * bfhi(q.y);
        acc[4] += pv * bflo(q.z);
        acc[5] += pv * bfhi(q.z);
        acc[6] += pv * bflo(q.w);
        acc[7] += pv * bfhi(q.w);
      }
    } else {
      for (int e = 0; e < take; ++e) {
        const int sl = e * 4 + head;
        const float pv = __shfl(pv_, sl);
        const int off = __shfl(off_, sl);
        uint4 q = *(const uint4*)(pb + (uint32_t)(off + laneByte));
        lsum += pv;
        acc[0] += pv * bflo(q.x);
        acc[1] += pv * bfhi(q.x);
        acc[2] += pv * bflo(q.y);
        acc[3] += pv * bfhi(q.y);
        acc[4] += pv * bflo(q.z);
        acc[5] += pv * bfhi(q.z);
        acc[6] += pv * bflo(q.w);
        acc[7] += pv * bfhi(q.w);
      }
    }
    sE = sEn;
    elv = elvn;
    i = i2;
    rem = rem2;
  }

  const float inv = 1.f / (lsum + 1e-9f);
  if (active) {
    float o[8];
#pragma unroll
    for (int j = 0; j < 8; ++j) {
      float v = acc[j] * inv + bv[j];
      if (ACT) v = (v > 0.f) ? v : 0.2f * v;
      o[j] = (d0 + j < DHR) ? v : 0.f;  // zero the head-pad (acc garbage there)
    }
    if constexpr (EMIT) {
      // emit pair-split A2 row (layer-2 GEMM A operand), stride 13*128 = 1664 B
      uint32_t hi8[8], lo8[8];
#pragma unroll
      for (int j = 0; j < 8; ++j) {
        hi8[j] = bf16rne(o[j]);
        float back = __uint_as_float(hi8[j] << 16);
        lo8[j] = bf16rne(o[j] - back);
      }
      uint4 hpx, lpx;
      hpx.x = hi8[0] | (hi8[1] << 16);
      hpx.y = hi8[2] | (hi8[3] << 16);
      hpx.z = hi8[4] | (hi8[5] << 16);
      hpx.w = hi8[6] | (hi8[7] << 16);
      lpx.x = lo8[0] | (lo8[1] << 16);
      lpx.y = lo8[2] | (lo8[3] << 16);
      lpx.z = lo8[4] | (lo8[5] << 16);
      lpx.w = lo8[6] | (lo8[7] << 16);
      const int kp = head * DHP + u * 8;  // 8-aligned (DHP=104)
      const int s2 = kp >> 5, q2 = (kp >> 3) & 3, xs = node & 7;
      char* rb = (char*)a2 + (size_t)node * 1664 + s2 * 128;
      *(uint4*)(rb + ((q2 ^ xs) << 4)) = hpx;
      *(uint4*)(rb + (((4 | q2) ^ xs) << 4)) = lpx;
    } else {
      float* orow = out + (size_t)node * (HEADS * DHR) + head * DHR + d0;
      *(float4*)orow = make_float4(o[0], o[1], o[2], o[3]);
      if (d0 + 7 < DHR) *(float4*)(orow + 4) = make_float4(o[4], o[5], o[6], o[7]);
    }
  }
}

extern "C" void kernel_launch(void* const* d_in, const int* in_sizes, int n_in,
                              void* d_out, int out_size, void* d_ws, size_t ws_size,
                              hipStream_t stream) {
  const float* init_emb = (const float*)d_in[0];
  const float* W1 = (const float*)d_in[1];
  const float* al1 = (const float*)d_in[2];
  const float* ar1 = (const float*)d_in[3];
  const float* b1 = (const float*)d_in[4];
  const float* W2 = (const float*)d_in[5];
  const float* al2 = (const float*)d_in[6];
  const float* ar2 = (const float*)d_in[7];
  const float* b2 = (const float*)d_in[8];
  const int* src = (const int*)d_in[9];
  const int* dst = (const int*)d_in[10];
  float* out = (float*)d_out;

  // workspace carve-up; A2 pair-split buffers live in d_out (dead until the final
  // aggregate, which only reads projh/el/er and then overwrites it).
  char* ws = (char*)d_ws;
  size_t off = 0;
  auto alloc = [&](size_t bytes) {
    void* p = ws + off;
    off += (bytes + 255) & ~((size_t)255);
    return p;
  };
  unsigned short* projh = (unsigned short*)alloc((size_t)NN * 512 * 2);  // bf16 proj (both layers)
  float* el = (float*)alloc((size_t)NN * HEADS * 4);
  float* er = (float*)alloc((size_t)NN * HEADS * 4);
  unsigned short* B2 = (unsigned short*)alloc((size_t)512 * 13 * 128);  // max ksteps=13
  int* row_ptr = (int*)alloc((size_t)(NN + 1) * 4);
  int* counts = (int*)alloc((size_t)NN * 4);
  int* srcs = (int*)alloc((size_t)NE * 4);
  unsigned short* A2 = (unsigned short*)d_out;  // up to MPAD*13*128 = 83.3MB <= 102.4MB

  // --- CSR build ---
  hipMemsetAsync(counts, 0, (size_t)NN * 4, stream);
  hist_kernel<<<(NE + 255) / 256, 256, 0, stream>>>(dst, counts, NE);
  scan_kernel<<<1, 1024, 0, stream>>>(counts, row_ptr, NN);
  hipMemsetAsync(counts, 0, (size_t)NN * 4, stream);
  scatter_kernel<<<(NE + 255) / 256, 256, 0, stream>>>(dst, src, row_ptr, counts, srcs, NE);

  // --- layer 1: K=300 -> ksteps=10, N=400 (head-padded 4x104) ---
  presplit_pairs<<<1024, 256, 0, stream>>>(init_emb, A2, NN, MPAD, 300, 10);
  presplit_pairs_b<<<dim3(1, 512), 64, 0, stream>>>(W1, B2, 300, 400, 10);
  gemm_pairs<<<dim3(4, MPAD / 128), 256, 0, stream>>>(A2, B2, projh, NN, 10, 400, 416, 100, 104, 41);
  el_er_kernel<100, 104><<<(NN * HEADS + 255) / 256, 256, 0, stream>>>(projh, al1, ar1, el, er);
  // aggregate L1 emits layer-2's pair-split A2 directly (act1 fused, x1 eliminated)
  aggregate2<104, 100, true, true><<<(NN + 3) / 4, 256, 0, stream>>>(projh, el, er, b1, row_ptr,
                                                                     srcs, nullptr, A2);

  // --- layer 2: head-padded K' = 4*104 = 416 -> ksteps=13, N=512 ---
  presplit_pairs_b2<<<dim3(1, 512), 64, 0, stream>>>(W2, B2);
  gemm_pairs<<<dim3(4, MPAD / 128), 256, 0, stream>>>(A2, B2, projh, NN, 13, 512, 512, 128, 128, 32);
  el_er_kernel<128, 128><<<(NN * HEADS + 255) / 256, 256, 0, stream>>>(projh, al2, ar2, el, er);
  aggregate2<128, 128, false, false><<<(NN + 3) / 4, 256, 0, stream>>>(projh, el, er, b2, row_ptr,
                                                                       srcs, out, nullptr);
}